// Round 1
// baseline (1518.581 us; speedup 1.0000x reference)
//
#include <hip/hip_runtime.h>

#define BB    4096
#define NIN   512
#define NREP  512
#define NOUT  640
#define RW    512
#define RB    64
#define NNZ   16384

// ---------------------------------------------------------------------------
// Kernel A: t[k] = sum_r Qw[r,k] * w[r]   (Qw: (327680, 512) row-major)
// grid 1280 blocks x 256 threads, 256 rows per block.
__global__ __launch_bounds__(256) void k_qwt(const float* __restrict__ Qw,
                                             const float* __restrict__ w,
                                             float* __restrict__ t) {
    __shared__ float4 red[256];
    const int tid = threadIdx.x;
    const int cb  = tid & 127;        // float4 column index 0..127
    const int p   = tid >> 7;         // row parity
    const long rbase = (long)blockIdx.x * 256;
    const float4* Qw4 = (const float4*)Qw;
    float4 acc = make_float4(0.f, 0.f, 0.f, 0.f);
    for (int i = p; i < 256; i += 2) {
        const long r = rbase + i;
        const float wr = w[r];
        const float4 q = Qw4[r * 128 + cb];
        acc.x += q.x * wr; acc.y += q.y * wr;
        acc.z += q.z * wr; acc.w += q.w * wr;
    }
    red[tid] = acc;
    __syncthreads();
    if (tid < 128) {
        float4 a = red[tid], b2 = red[tid + 128];
        atomicAdd(&t[cb * 4 + 0], a.x + b2.x);
        atomicAdd(&t[cb * 4 + 1], a.y + b2.y);
        atomicAdd(&t[cb * 4 + 2], a.z + b2.z);
        atomicAdd(&t[cb * 4 + 3], a.w + b2.w);
    }
}

// ---------------------------------------------------------------------------
// Kernel B: Wp[r] = sum_k Qw[r,k] * t[k]   (wave per row, t hoisted per lane)
__global__ __launch_bounds__(256) void k_wp(const float* __restrict__ Qw,
                                            const float* __restrict__ t,
                                            float* __restrict__ Wp) {
    __shared__ float4 ts[128];
    const int tid = threadIdx.x;
    if (tid < 128) ts[tid] = ((const float4*)t)[tid];
    __syncthreads();
    const int lane = tid & 63;
    const int wave = tid >> 6;
    const float4 tv1 = ts[lane];
    const float4 tv2 = ts[64 + lane];
    const float4* Qw4 = (const float4*)Qw;
    const long rbase = (long)blockIdx.x * 256;
    for (int i = wave; i < 256; i += 4) {
        const long r = rbase + i;
        const float4 q1 = Qw4[r * 128 + lane];
        const float4 q2 = Qw4[r * 128 + 64 + lane];
        float s = q1.x * tv1.x + q1.y * tv1.y + q1.z * tv1.z + q1.w * tv1.w
                + q2.x * tv2.x + q2.y * tv2.y + q2.z * tv2.z + q2.w * tv2.w;
        #pragma unroll
        for (int off = 32; off > 0; off >>= 1) s += __shfl_xor(s, off, 64);
        if (lane == 0) Wp[r] = s;
    }
}

// ---------------------------------------------------------------------------
// Kernel C: bp = Qb @ (Qb^T @ b)   (Qb: (640,64) row-major) — single block
__global__ __launch_bounds__(256) void k_bp(const float* __restrict__ Qb,
                                            const float* __restrict__ b,
                                            float* __restrict__ bp) {
    __shared__ float part[4][64];
    __shared__ float t2[64];
    const int tid = threadIdx.x;
    const int j = tid & 63, p = tid >> 6;
    float acc = 0.f;
    for (int o = p * 160; o < (p + 1) * 160; ++o) acc += Qb[o * 64 + j] * b[o];
    part[p][j] = acc;
    __syncthreads();
    if (tid < 64) t2[tid] = part[0][tid] + part[1][tid] + part[2][tid] + part[3][tid];
    __syncthreads();
    for (int o = tid; o < NOUT; o += 256) {
        float a = 0.f;
        #pragma unroll 8
        for (int jj = 0; jj < 64; ++jj) a += Qb[o * 64 + jj] * t2[jj];
        bp[o] = a;
    }
}

// ---------------------------------------------------------------------------
// Kernel D: lin = x @ Wp^T + bp   (M=4096, N=640, K=512), fp32 tiled.
// 64x64 tile per block, 4x4 micro-tile per thread (16-strided rows/cols so
// ds_read_b128 is <=2-way bank-aliased).
__global__ __launch_bounds__(256) void k_gemm(const float* __restrict__ x,
                                              const float* __restrict__ Wp,
                                              const float* __restrict__ bp,
                                              float* __restrict__ lin) {
    __shared__ float xs[64][36];
    __shared__ float wls[64][36];
    const int tid = threadIdx.x;
    const int bx = blockIdx.x;        // N tile: 0..9
    const int by = blockIdx.y;        // M tile: 0..63
    const int row0 = by * 64, col0 = bx * 64;
    const int lr = tid >> 3;          // 0..31 (staging row)
    const int lc = (tid & 7) * 4;     // 0..28 (staging col, float4)
    const int tx = tid & 15, ty = tid >> 4;
    float acc[4][4] = {};
    for (int kt = 0; kt < NIN; kt += 32) {
        const float4 xv0 = *(const float4*)&x[(long)(row0 + lr) * NIN + kt + lc];
        const float4 xv1 = *(const float4*)&x[(long)(row0 + lr + 32) * NIN + kt + lc];
        const float4 wv0 = *(const float4*)&Wp[(long)(col0 + lr) * NIN + kt + lc];
        const float4 wv1 = *(const float4*)&Wp[(long)(col0 + lr + 32) * NIN + kt + lc];
        __syncthreads();
        *(float4*)&xs[lr][lc]        = xv0;
        *(float4*)&xs[lr + 32][lc]   = xv1;
        *(float4*)&wls[lr][lc]       = wv0;
        *(float4*)&wls[lr + 32][lc]  = wv1;
        __syncthreads();
        #pragma unroll
        for (int kk = 0; kk < 32; kk += 4) {
            float4 a[4], bv[4];
            #pragma unroll
            for (int i = 0; i < 4; ++i) a[i]  = *(const float4*)&xs[ty + 16 * i][kk];
            #pragma unroll
            for (int j = 0; j < 4; ++j) bv[j] = *(const float4*)&wls[tx + 16 * j][kk];
            #pragma unroll
            for (int i = 0; i < 4; ++i)
                #pragma unroll
                for (int j = 0; j < 4; ++j)
                    acc[i][j] += a[i].x * bv[j].x + a[i].y * bv[j].y
                               + a[i].z * bv[j].z + a[i].w * bv[j].w;
        }
    }
    float bpv[4];
    #pragma unroll
    for (int j = 0; j < 4; ++j) bpv[j] = bp[col0 + tx + 16 * j];
    #pragma unroll
    for (int i = 0; i < 4; ++i) {
        const long gr = row0 + ty + 16 * i;
        #pragma unroll
        for (int j = 0; j < 4; ++j)
            lin[gr * NOUT + col0 + tx + 16 * j] = acc[i][j] + bpv[j];
    }
}

// ---------------------------------------------------------------------------
// Kernel E: bilinear scatter + gated nonlinearity. 4 batch rows per block.
__global__ __launch_bounds__(256) void k_epi(const float* __restrict__ lin,
                                             const float* __restrict__ bip,
                                             const int* __restrict__ bsrc,
                                             const int* __restrict__ brow,
                                             const int* __restrict__ bcol,
                                             const int* __restrict__ gidx,
                                             float* __restrict__ out) {
    __shared__ float ls[4][NOUT];
    __shared__ float bs[4][NOUT];
    const int tid = threadIdx.x;
    const long b0 = (long)blockIdx.x * 4;
    for (int rr = 0; rr < 4; ++rr)
        for (int j = tid; j < NOUT; j += 256) {
            ls[rr][j] = lin[(b0 + rr) * NOUT + j];
            bs[rr][j] = 0.f;
        }
    __syncthreads();
    for (int k = tid; k < NNZ; k += 256) {
        const float p = bip[k];
        const int s = bsrc[k], r = brow[k], c = bcol[k];
        #pragma unroll
        for (int rr = 0; rr < 4; ++rr)
            atomicAdd(&bs[rr][r], p * ls[rr][s] * ls[rr][c]);
    }
    __syncthreads();
    for (int rr = 0; rr < 4; ++rr)
        for (int j = tid; j < NOUT; j += 256)
            ls[rr][j] = 0.1f * bs[rr][j] + ls[rr][j];   // preact
    __syncthreads();
    for (int rr = 0; rr < 4; ++rr)
        for (int j = tid; j < NREP; j += 256) {
            const float v = ls[rr][j];
            const float g = ls[rr][gidx[j]];
            out[(b0 + rr) * NREP + j] = v * (1.f / (1.f + __expf(-g)));
        }
}

// ---------------------------------------------------------------------------
extern "C" void kernel_launch(void* const* d_in, const int* in_sizes, int n_in,
                              void* d_out, int out_size, void* d_ws, size_t ws_size,
                              hipStream_t stream) {
    const float* x    = (const float*)d_in[0];
    const float* Ww   = (const float*)d_in[1];
    const float* b    = (const float*)d_in[2];
    const float* Qw   = (const float*)d_in[3];
    const float* Qb   = (const float*)d_in[4];
    const float* bip  = (const float*)d_in[5];
    const int*   bsrc = (const int*)d_in[6];
    const int*   brow = (const int*)d_in[7];
    const int*   bcol = (const int*)d_in[8];
    const int*   gidx = (const int*)d_in[9];
    float* out = (float*)d_out;

    float* ws  = (float*)d_ws;
    float* t   = ws;                       // 512 floats
    float* bp  = ws + 512;                 // 640 floats (starts at 512)
    float* Wp  = ws + 1152;                // 327680 floats, 16B-aligned
    float* lin = ws + 1152 + (long)NOUT * NIN;  // B*NOUT floats, 16B-aligned

    hipMemsetAsync(t, 0, RW * sizeof(float), stream);
    k_qwt<<<1280, 256, 0, stream>>>(Qw, Ww, t);
    k_bp<<<1, 256, 0, stream>>>(Qb, b, bp);
    k_wp<<<1280, 256, 0, stream>>>(Qw, t, Wp);
    dim3 gg(10, 64);
    k_gemm<<<gg, 256, 0, stream>>>(x, Wp, bp, lin);
    k_epi<<<BB / 4, 256, 0, stream>>>(lin, bip, bsrc, brow, bcol, gidx, out);
}